// Round 8
// baseline (1168.177 us; speedup 1.0000x reference)
//
#include <hip/hip_runtime.h>
#include <math.h>

#define BATCH 8
#define SEQ 512
#define NVAR 1024
#define DM 512
#define NH 8
#define DH 64
#define NE 8
#define NF 8
#define NL 2
#define NTOK (BATCH*NVAR)   // 8192
#define LN_EPS 1e-5f
#define LSC 2048.0f
#define ILSC (1.0f/2048.0f)

typedef __attribute__((ext_vector_type(8))) _Float16 f16x8;
typedef __attribute__((ext_vector_type(4))) float f32x4;
typedef unsigned int uint;
#define MFMA16 __builtin_amdgcn_mfma_f32_16x16x32_f16

__device__ __forceinline__ void fsplit(float v, _Float16& hi, _Float16& lo) {
    hi = (_Float16)v;
    lo = (_Float16)((v - (float)hi) * LSC);
}
__device__ __forceinline__ float frec(_Float16 hi, _Float16 lo) {
    return (float)hi + (float)lo * ILSC;
}

// pack two (hi,lo) half-pairs per dword-pair: out = h | l<<16 per element
__device__ __forceinline__ void pack8(uint4 H, uint4 L, uint4& O0, uint4& O1) {
    O0.x = __builtin_amdgcn_perm(L.x, H.x, 0x05040100u);
    O0.y = __builtin_amdgcn_perm(L.x, H.x, 0x07060302u);
    O0.z = __builtin_amdgcn_perm(L.y, H.y, 0x05040100u);
    O0.w = __builtin_amdgcn_perm(L.y, H.y, 0x07060302u);
    O1.x = __builtin_amdgcn_perm(L.z, H.z, 0x05040100u);
    O1.y = __builtin_amdgcn_perm(L.z, H.z, 0x07060302u);
    O1.z = __builtin_amdgcn_perm(L.w, H.w, 0x05040100u);
    O1.w = __builtin_amdgcn_perm(L.w, H.w, 0x07060302u);
}
// unpack 8 packed u32 -> hi f16x8, lo f16x8
__device__ __forceinline__ void unpack8(const uint* p, f16x8& hf, f16x8& lf) {
    uint4 A = *(const uint4*)p;
    uint4 B = *(const uint4*)(p + 4);
    uint4 H, L;
    H.x = __builtin_amdgcn_perm(A.y, A.x, 0x05040100u);
    L.x = __builtin_amdgcn_perm(A.y, A.x, 0x07060302u);
    H.y = __builtin_amdgcn_perm(A.w, A.z, 0x05040100u);
    L.y = __builtin_amdgcn_perm(A.w, A.z, 0x07060302u);
    H.z = __builtin_amdgcn_perm(B.y, B.x, 0x05040100u);
    L.z = __builtin_amdgcn_perm(B.y, B.x, 0x07060302u);
    H.w = __builtin_amdgcn_perm(B.w, B.z, 0x05040100u);
    L.w = __builtin_amdgcn_perm(B.w, B.z, 0x07060302u);
    hf = __builtin_bit_cast(f16x8, H);
    lf = __builtin_bit_cast(f16x8, L);
}

// ---------------------------------------------------------------- RevIN stats
__global__ __launch_bounds__(256) void revin_stats_kernel(
        const float* __restrict__ x, float* __restrict__ mean, float* __restrict__ stdd) {
    int blk = blockIdx.x;            // b*16 + ntile
    int b = blk >> 4;
    int n0 = (blk & 15) << 6;
    int t = threadIdx.x;
    int ni = t & 63, sg = t >> 6;
    float s = 0.f, ss = 0.f;
    for (int sidx = sg; sidx < SEQ; sidx += 4) {
        float v = x[((size_t)b*SEQ + sidx)*NVAR + n0 + ni];
        s += v; ss += v*v;
    }
    __shared__ float rs[4][64], rq[4][64];
    rs[sg][ni] = s; rq[sg][ni] = ss;
    __syncthreads();
    if (t < 64) {
        float su = rs[0][t] + rs[1][t] + rs[2][t] + rs[3][t];
        float sq = rq[0][t] + rq[1][t] + rq[2][t] + rq[3][t];
        float m  = su / (float)SEQ;
        float var = sq / (float)SEQ - m*m;
        int n = n0 + t;
        mean[b*NVAR + n] = m;
        stdd[b*NVAR + n] = sqrtf(var + LN_EPS);
    }
}

// ------------------------------- RevIN normalize + transpose (split f16 out)
__global__ __launch_bounds__(256) void revin_norm_kernel(
        const float* __restrict__ x, const float* __restrict__ mean, const float* __restrict__ stdd,
        const float* __restrict__ rw, const float* __restrict__ rb,
        _Float16* __restrict__ xnhi, _Float16* __restrict__ xnlo) {
    __shared__ float tile[32][33];
    int n0 = blockIdx.x << 5, s0 = blockIdx.y << 5, b = blockIdx.z;
    int t = threadIdx.x;
    int j = t & 31, i0 = t >> 5;
    for (int ii = i0; ii < 32; ii += 8)
        tile[ii][j] = x[((size_t)b*SEQ + s0 + ii)*NVAR + n0 + j];
    __syncthreads();
    int si = t & 31, j0 = t >> 5;
    for (int nj = j0; nj < 32; nj += 8) {
        int n = n0 + nj;
        float m = mean[b*NVAR + n], sd = stdd[b*NVAR + n];
        float v = (tile[si][nj] - m) / sd * rw[n] + rb[n];
        _Float16 h_, l_; fsplit(v, h_, l_);
        size_t idx = ((size_t)b*NVAR + n)*SEQ + s0 + si;
        xnhi[idx] = h_; xnlo[idx] = l_;
    }
}

// ----------------------- weight transpose+split: [K,N] -> [N,K] f16 hi/lo
struct WSrcs { const float* p[9]; };
__global__ __launch_bounds__(256) void transpose_w_kernel(
        WSrcs srcs, _Float16* __restrict__ whi, _Float16* __restrict__ wlo) {
    const float* W = srcs.p[blockIdx.z];
    _Float16* oh = whi + (size_t)blockIdx.z * DM * DM;
    _Float16* ol = wlo + (size_t)blockIdx.z * DM * DM;
    __shared__ float tile[64][65];
    int k0 = blockIdx.x << 6, n0 = blockIdx.y << 6;
    int t = threadIdx.x;
    for (int idx = t; idx < 4096; idx += 256) {
        int k = idx >> 6, n = idx & 63;
        tile[k][n] = W[(size_t)(k0 + k)*DM + n0 + n];
    }
    __syncthreads();
    for (int idx = t; idx < 4096; idx += 256) {
        int n = idx >> 6, k = idx & 63;
        _Float16 h_, l_; fsplit(tile[k][n], h_, l_);
        size_t o = (size_t)(n0 + n)*DM + k0 + k;
        oh[o] = h_; ol[o] = l_;
    }
}

// ------------------------------------------- fp16x2 MFMA GEMM (fp32-grade)
__global__ __launch_bounds__(256) void gemm_f16x2_kernel(
        const _Float16* __restrict__ Ahg, const _Float16* __restrict__ Alg,
        const _Float16* __restrict__ Whg, const _Float16* __restrict__ Wlg,
        const float* __restrict__ bias, float* __restrict__ C,
        _Float16* __restrict__ Chi, _Float16* __restrict__ Clo,
        int M, int K, int N) {
    __shared__ _Float16 sAh[128][40], sAl[128][40];
    __shared__ _Float16 sBh[64][40],  sBl[64][40];
    int bm = blockIdx.y << 7, bn = blockIdx.x << 6;
    int t = threadIdx.x;
    int w = t >> 6, lane = t & 63, m16 = lane & 15, quad = lane >> 4;
    int ra = t >> 1,  ca = (t & 1) << 4;   // A: 128 rows x 2 groups of 16
    int rb = t >> 2,  cb = (t & 3) << 3;   // B: 64 rows x 4 groups of 8
    f32x4 a1[2][4] = {}, a2[2][4] = {};
    for (int k0 = 0; k0 < K; k0 += 32) {
        size_t ga = (size_t)(bm + ra)*K + k0 + ca;
        size_t gb = (size_t)(bn + rb)*K + k0 + cb;
        *(uint4*)&sAh[ra][ca]   = *(const uint4*)&Ahg[ga];
        *(uint4*)&sAh[ra][ca+8] = *(const uint4*)&Ahg[ga + 8];
        *(uint4*)&sAl[ra][ca]   = *(const uint4*)&Alg[ga];
        *(uint4*)&sAl[ra][ca+8] = *(const uint4*)&Alg[ga + 8];
        *(uint4*)&sBh[rb][cb]   = *(const uint4*)&Whg[gb];
        *(uint4*)&sBl[rb][cb]   = *(const uint4*)&Wlg[gb];
        __syncthreads();
        f16x8 bh_[4], bl_[4];
#pragma unroll
        for (int nt = 0; nt < 4; ++nt) {
            bh_[nt] = *(const f16x8*)&sBh[nt*16 + m16][quad*8];
            bl_[nt] = *(const f16x8*)&sBl[nt*16 + m16][quad*8];
        }
#pragma unroll
        for (int h2 = 0; h2 < 2; ++h2) {
            f16x8 ah = *(const f16x8*)&sAh[w*32 + h2*16 + m16][quad*8];
            f16x8 al = *(const f16x8*)&sAl[w*32 + h2*16 + m16][quad*8];
#pragma unroll
            for (int nt = 0; nt < 4; ++nt) {
                a1[h2][nt] = MFMA16(ah, bh_[nt], a1[h2][nt], 0, 0, 0);
                a2[h2][nt] = MFMA16(ah, bl_[nt], a2[h2][nt], 0, 0, 0);
                a2[h2][nt] = MFMA16(al, bh_[nt], a2[h2][nt], 0, 0, 0);
            }
        }
        __syncthreads();
    }
#pragma unroll
    for (int h2 = 0; h2 < 2; ++h2)
#pragma unroll
        for (int nt = 0; nt < 4; ++nt) {
            int col = bn + nt*16 + m16;
            float bv = bias[col];
#pragma unroll
            for (int r = 0; r < 4; ++r) {
                size_t row = bm + w*32 + h2*16 + quad*4 + r;
                float v = a1[h2][nt][r] + a2[h2][nt][r]*ILSC + bv;
                if (C) C[row*N + col] = v;
                if (Chi) {
                    _Float16 h_, l_; fsplit(v, h_, l_);
                    Chi[row*N + col] = h_; Clo[row*N + col] = l_;
                }
            }
        }
}

// ------------------- fp16x2 GEMM, transposed split output (V projection)
__global__ __launch_bounds__(256) void gemm_f16x2_vt_kernel(
        const _Float16* __restrict__ Ahg, const _Float16* __restrict__ Alg,
        const _Float16* __restrict__ Whg, const _Float16* __restrict__ Wlg,
        const float* __restrict__ bias,
        _Float16* __restrict__ vthi, _Float16* __restrict__ vtlo) {
    __shared__ _Float16 sAh[128][40], sAl[128][40];
    __shared__ _Float16 sBh[64][40],  sBl[64][40];
    __shared__ float Ct[128][65];
    int bm = blockIdx.y << 7, bn = blockIdx.x << 6;
    int t = threadIdx.x;
    int w = t >> 6, lane = t & 63, m16 = lane & 15, quad = lane >> 4;
    int ra = t >> 1,  ca = (t & 1) << 4;
    int rb = t >> 2,  cb = (t & 3) << 3;
    f32x4 a1[2][4] = {}, a2[2][4] = {};
    for (int k0 = 0; k0 < DM; k0 += 32) {
        size_t ga = (size_t)(bm + ra)*DM + k0 + ca;
        size_t gb = (size_t)(bn + rb)*DM + k0 + cb;
        *(uint4*)&sAh[ra][ca]   = *(const uint4*)&Ahg[ga];
        *(uint4*)&sAh[ra][ca+8] = *(const uint4*)&Ahg[ga + 8];
        *(uint4*)&sAl[ra][ca]   = *(const uint4*)&Alg[ga];
        *(uint4*)&sAl[ra][ca+8] = *(const uint4*)&Alg[ga + 8];
        *(uint4*)&sBh[rb][cb]   = *(const uint4*)&Whg[gb];
        *(uint4*)&sBl[rb][cb]   = *(const uint4*)&Wlg[gb];
        __syncthreads();
        f16x8 bh_[4], bl_[4];
#pragma unroll
        for (int nt = 0; nt < 4; ++nt) {
            bh_[nt] = *(const f16x8*)&sBh[nt*16 + m16][quad*8];
            bl_[nt] = *(const f16x8*)&sBl[nt*16 + m16][quad*8];
        }
#pragma unroll
        for (int h2 = 0; h2 < 2; ++h2) {
            f16x8 ah = *(const f16x8*)&sAh[w*32 + h2*16 + m16][quad*8];
            f16x8 al = *(const f16x8*)&sAl[w*32 + h2*16 + m16][quad*8];
#pragma unroll
            for (int nt = 0; nt < 4; ++nt) {
                a1[h2][nt] = MFMA16(ah, bh_[nt], a1[h2][nt], 0, 0, 0);
                a2[h2][nt] = MFMA16(ah, bl_[nt], a2[h2][nt], 0, 0, 0);
                a2[h2][nt] = MFMA16(al, bh_[nt], a2[h2][nt], 0, 0, 0);
            }
        }
        __syncthreads();
    }
#pragma unroll
    for (int h2 = 0; h2 < 2; ++h2)
#pragma unroll
        for (int nt = 0; nt < 4; ++nt) {
            float bv = bias[bn + nt*16 + m16];
#pragma unroll
            for (int r = 0; r < 4; ++r)
                Ct[w*32 + h2*16 + quad*4 + r][nt*16 + m16] = a1[h2][nt][r] + a2[h2][nt][r]*ILSC + bv;
        }
    __syncthreads();
    int b = bm >> 10, tokn0 = bm & 1023, hh = bn >> 6;
    int dh = t >> 2, tg = (t & 3) << 4;
    size_t rowb = ((size_t)(b*8 + hh)*64 + dh)*NVAR + tokn0;
    for (int hb = 0; hb < 2; ++hb) {
        int tl0 = hb*64 + tg;
        unsigned short hbuf[16], lbuf[16];
#pragma unroll
        for (int i = 0; i < 16; ++i) {
            _Float16 h_, l_; fsplit(Ct[tl0 + i][dh], h_, l_);
            hbuf[i] = __builtin_bit_cast(unsigned short, h_);
            lbuf[i] = __builtin_bit_cast(unsigned short, l_);
        }
        uint4 uh0, uh1, ul0, ul1;
        uh0.x = hbuf[0]|(hbuf[1]<<16);  uh0.y = hbuf[2]|(hbuf[3]<<16);
        uh0.z = hbuf[4]|(hbuf[5]<<16);  uh0.w = hbuf[6]|(hbuf[7]<<16);
        uh1.x = hbuf[8]|(hbuf[9]<<16);  uh1.y = hbuf[10]|(hbuf[11]<<16);
        uh1.z = hbuf[12]|(hbuf[13]<<16);uh1.w = hbuf[14]|(hbuf[15]<<16);
        ul0.x = lbuf[0]|(lbuf[1]<<16);  ul0.y = lbuf[2]|(lbuf[3]<<16);
        ul0.z = lbuf[4]|(lbuf[5]<<16);  ul0.w = lbuf[6]|(lbuf[7]<<16);
        ul1.x = lbuf[8]|(lbuf[9]<<16);  ul1.y = lbuf[10]|(lbuf[11]<<16);
        ul1.z = lbuf[12]|(lbuf[13]<<16);ul1.w = lbuf[14]|(lbuf[15]<<16);
        *(uint4*)&vthi[rowb + tl0]     = uh0;
        *(uint4*)&vthi[rowb + tl0 + 8] = uh1;
        *(uint4*)&vtlo[rowb + tl0]     = ul0;
        *(uint4*)&vtlo[rowb + tl0 + 8] = ul1;
    }
}

// ------------------------------------- flash attention, fp16x2 MFMA, v2
// Block: 128 q-rows (4 waves x 2 m-tiles of 16), one bh.  Grid 512.
// K/V staged packed-u32 in LDS; Q in registers; P per-wave (no barrier).
__global__ __launch_bounds__(256) void attn_f16x2_kernel(
        const _Float16* __restrict__ qh, const _Float16* __restrict__ ql,
        const _Float16* __restrict__ kh, const _Float16* __restrict__ kl,
        const _Float16* __restrict__ vth, const _Float16* __restrict__ vtl,
        _Float16* __restrict__ oh, _Float16* __restrict__ ol) {
    __shared__ uint KV[2][64][68];   // [0]=K rows=key, [1]=V rows=dh; packed h|l<<16
    __shared__ uint Pu[128][68];     // P rows=q (wave-private 32-row slices)
    int blk = blockIdx.x;
    int qt = blk & 7, bh = blk >> 3;
    int b = bh >> 3, hh = bh & 7;
    int q0 = qt << 7;                // 128 q rows
    int t = threadIdx.x;
    int w = t >> 6, lane = t & 63;
    int m16 = lane & 15, quad = lane >> 4;
    size_t bbase = (size_t)b * NVAR;
    size_t vbase = (size_t)bh * DH * NVAR;

    // Q fragments in registers
    f16x8 qfh[2][2], qfl[2][2];
#pragma unroll
    for (int mt = 0; mt < 2; ++mt) {
        size_t rowp = (bbase + q0 + w*32 + mt*16 + m16)*DM + hh*DH;
#pragma unroll
        for (int ks = 0; ks < 2; ++ks) {
            qfh[mt][ks] = *(const f16x8*)&qh[rowp + ks*32 + quad*8];
            qfl[mt][ks] = *(const f16x8*)&ql[rowp + ks*32 + quad*8];
        }
    }
    float mrow[2][4], lrow[2][4];
#pragma unroll
    for (int mt = 0; mt < 2; ++mt)
#pragma unroll
        for (int r = 0; r < 4; ++r) { mrow[mt][r] = -1e30f; lrow[mt][r] = 0.f; }
    f32x4 o1[2][4] = {}, o2[2][4] = {};

    for (int n0 = 0; n0 < NVAR; n0 += 64) {
        // stage K and V^T packed
#pragma unroll
        for (int p = 0; p < 2; ++p) {
            int g = t + p*256, rr = g >> 3, cg = g & 7;
            size_t ka = (bbase + n0 + rr)*DM + hh*DH + cg*8;
            uint4 H = *(const uint4*)&kh[ka];
            uint4 L = *(const uint4*)&kl[ka];
            uint4 O0, O1; pack8(H, L, O0, O1);
            *(uint4*)&KV[0][rr][cg*8]     = O0;
            *(uint4*)&KV[0][rr][cg*8 + 4] = O1;
            size_t va = vbase + (size_t)rr*NVAR + n0 + cg*8;
            H = *(const uint4*)&vth[va];
            L = *(const uint4*)&vtl[va];
            pack8(H, L, O0, O1);
            *(uint4*)&KV[1][rr][cg*8]     = O0;
            *(uint4*)&KV[1][rr][cg*8 + 4] = O1;
        }
        __syncthreads();

        // S = Q K^T for both m-tiles
        f32x4 s1[2][4] = {}, s2[2][4] = {};
#pragma unroll
        for (int ks = 0; ks < 2; ++ks)
#pragma unroll
            for (int nt = 0; nt < 4; ++nt) {
                f16x8 bh_, bl_;
                unpack8(&KV[0][nt*16 + m16][ks*32 + quad*8], bh_, bl_);
#pragma unroll
                for (int mt = 0; mt < 2; ++mt) {
                    s1[mt][nt] = MFMA16(qfh[mt][ks], bh_, s1[mt][nt], 0, 0, 0);
                    s2[mt][nt] = MFMA16(qfh[mt][ks], bl_, s2[mt][nt], 0, 0, 0);
                    s2[mt][nt] = MFMA16(qfl[mt][ks], bh_, s2[mt][nt], 0, 0, 0);
                }
            }

        // online softmax + packed P write (wave-private rows; no barrier)
#pragma unroll
        for (int mt = 0; mt < 2; ++mt)
#pragma unroll
            for (int r = 0; r < 4; ++r) {
                float sv[4];
#pragma unroll
                for (int nt = 0; nt < 4; ++nt)
                    sv[nt] = s1[mt][nt][r]*0.125f + s2[mt][nt][r]*(0.125f*ILSC);
                float mx = fmaxf(fmaxf(sv[0], sv[1]), fmaxf(sv[2], sv[3]));
                mx = fmaxf(mx, __shfl_xor(mx, 1));
                mx = fmaxf(mx, __shfl_xor(mx, 2));
                mx = fmaxf(mx, __shfl_xor(mx, 4));
                mx = fmaxf(mx, __shfl_xor(mx, 8));
                float mnew = fmaxf(mrow[mt][r], mx);
                float alpha = __expf(mrow[mt][r] - mnew);
                float rs = 0.f;
                int prow = w*32 + mt*16 + quad*4 + r;
#pragma unroll
                for (int nt = 0; nt < 4; ++nt) {
                    float pv = __expf(sv[nt] - mnew);
                    rs += pv;
                    _Float16 hp, lp; fsplit(pv, hp, lp);
                    Pu[prow][nt*16 + m16] =
                        (uint)__builtin_bit_cast(unsigned short, hp) |
                        ((uint)__builtin_bit_cast(unsigned short, lp) << 16);
                }
                rs += __shfl_xor(rs, 1);
                rs += __shfl_xor(rs, 2);
                rs += __shfl_xor(rs, 4);
                rs += __shfl_xor(rs, 8);
                lrow[mt][r] = lrow[mt][r]*alpha + rs;
                mrow[mt][r] = mnew;
#pragma unroll
                for (int nt = 0; nt < 4; ++nt) { o1[mt][nt][r] *= alpha; o2[mt][nt][r] *= alpha; }
            }

        // O += P V   (P A-frag from own rows; V B-frag from LDS)
#pragma unroll
        for (int ks = 0; ks < 2; ++ks) {
            f16x8 ph[2], pl[2];
#pragma unroll
            for (int mt = 0; mt < 2; ++mt)
                unpack8(&Pu[w*32 + mt*16 + m16][ks*32 + quad*8], ph[mt], pl[mt]);
#pragma unroll
            for (int nt = 0; nt < 4; ++nt) {
                f16x8 vh_, vl_;
                unpack8(&KV[1][nt*16 + m16][ks*32 + quad*8], vh_, vl_);
#pragma unroll
                for (int mt = 0; mt < 2; ++mt) {
                    o1[mt][nt] = MFMA16(ph[mt], vh_, o1[mt][nt], 0, 0, 0);
                    o2[mt][nt] = MFMA16(ph[mt], vl_, o2[mt][nt], 0, 0, 0);
                    o2[mt][nt] = MFMA16(pl[mt], vh_, o2[mt][nt], 0, 0, 0);
                }
            }
        }
        __syncthreads();
    }
#pragma unroll
    for (int mt = 0; mt < 2; ++mt)
#pragma unroll
        for (int r = 0; r < 4; ++r) {
            float inv = 1.0f / lrow[mt][r];
            size_t rowp = (bbase + q0 + w*32 + mt*16 + quad*4 + r)*DM + hh*DH;
#pragma unroll
            for (int nt = 0; nt < 4; ++nt) {
                float ov = (o1[mt][nt][r] + o2[mt][nt][r]*ILSC) * inv;
                _Float16 h_, l_; fsplit(ov, h_, l_);
                oh[rowp + nt*16 + m16] = h_;
                ol[rowp + nt*16 + m16] = l_;
            }
        }
}

// ---------------------------------------------------------------- LayerNorm
__global__ __launch_bounds__(256) void ln_kernel(
        _Float16* __restrict__ hhi, _Float16* __restrict__ hlo,
        const float* __restrict__ res,
        const float* __restrict__ w, const float* __restrict__ b) {
    int rowi = blockIdx.x, t = threadIdx.x;
    size_t base = (size_t)rowi * DM;
    float v0 = frec(hhi[base + t], hlo[base + t]);
    float v1 = frec(hhi[base + t + 256], hlo[base + t + 256]);
    if (res) { v0 += res[base + t]; v1 += res[base + t + 256]; }
    __shared__ float rs[256], rq[256];
    rs[t] = v0 + v1; rq[t] = v0*v0 + v1*v1;
    __syncthreads();
    for (int off = 128; off > 0; off >>= 1) {
        if (t < off) { rs[t] += rs[t+off]; rq[t] += rq[t+off]; }
        __syncthreads();
    }
    float m = rs[0] / (float)DM;
    float var = rq[0] / (float)DM - m*m;
    float inv = 1.0f / sqrtf(var + LN_EPS);
    float y0 = (v0 - m)*inv * w[t]       + b[t];
    float y1 = (v1 - m)*inv * w[t + 256] + b[t + 256];
    _Float16 h0, l0, h1, l1;
    fsplit(y0, h0, l0); fsplit(y1, h1, l1);
    hhi[base + t] = h0;       hlo[base + t] = l0;
    hhi[base + t + 256] = h1; hlo[base + t + 256] = l1;
}

__device__ __forceinline__ float gelu_exact(float xv) {
    return 0.5f * xv * (1.0f + erff(xv * 0.70710678118654752f));
}

// ---------------------------------------------------------------- MoE FFN
__global__ __launch_bounds__(256) void moe_kernel(
        const _Float16* __restrict__ hhi, const _Float16* __restrict__ hlo,
        float* __restrict__ out,
        const float* __restrict__ gW, const float* __restrict__ W1, const float* __restrict__ b1,
        const float* __restrict__ W2, const float* __restrict__ b2) {
    int tok = blockIdx.x, t = threadIdx.x;
    __shared__ float hs[DM];
    __shared__ float red[32][8];
    __shared__ float glog[8];
    __shared__ float hmid[8];
    __shared__ float wsel[2];
    __shared__ int   esel[2];
    size_t base = (size_t)tok * DM;
    hs[t] = frec(hhi[base + t], hlo[base + t]);
    hs[t + 256] = frec(hhi[base + t + 256], hlo[base + t + 256]);
    __syncthreads();
    int e = t & 7, i0 = t >> 3;
    {
        float a = 0.f;
        for (int i = i0; i < DM; i += 32) a += hs[i] * gW[i*NE + e];
        red[i0][e] = a;
    }
    __syncthreads();
    if (t < 8) { float sv = 0.f; for (int i = 0; i < 32; ++i) sv += red[i][t]; glog[t] = sv; }
    __syncthreads();
    if (t == 0) {
        float m0 = -1e30f, m1 = -1e30f; int s0i = 0, s1i = 0;
        for (int ei = 0; ei < 8; ++ei) {
            float vv = glog[ei];
            if (vv > m0) { m1 = m0; s1i = s0i; m0 = vv; s0i = ei; }
            else if (vv > m1) { m1 = vv; s1i = ei; }
        }
        float Z = 0.f;
        for (int ei = 0; ei < 8; ++ei) Z += expf(glog[ei] - m0);
        wsel[0] = 1.0f / Z;
        wsel[1] = expf(m1 - m0) / Z;
        esel[0] = s0i; esel[1] = s1i;
    }
    __syncthreads();
    float o0 = 0.f, o1 = 0.f;
    for (int ks = 0; ks < 2; ++ks) {
        int ee = esel[ks]; float wk = wsel[ks];
        int f = t & 7;
        float a = 0.f;
        for (int i = i0; i < DM; i += 32) a += hs[i] * W1[((size_t)ee*DM + i)*NF + f];
        red[i0][f] = a;
        __syncthreads();
        if (t < 8) {
            float sv = b1[ee*NF + t];
            for (int i = 0; i < 32; ++i) sv += red[i][t];
            hmid[t] = gelu_exact(sv);
        }
        __syncthreads();
        float s0v = b2[ee*DM + t], s1v = b2[ee*DM + t + 256];
#pragma unroll
        for (int i = 0; i < NF; ++i) {
            float hm = hmid[i];
            const float* wp = W2 + ((size_t)ee*NF + i)*DM;
            s0v += hm * wp[t]; s1v += hm * wp[t + 256];
        }
        o0 += wk * s0v; o1 += wk * s1v;
        __syncthreads();
    }
    out[base + t] = o0; out[base + t + 256] = o1;
}

// ------------------------------------------------------------- head: init
__global__ __launch_bounds__(64) void head_init_kernel(int* __restrict__ cnt) {
    if (threadIdx.x < NE) cnt[threadIdx.x] = 0;
}

// ------------------------------------------------------------- head: gate
__global__ __launch_bounds__(256) void head_gate_kernel(
        const _Float16* __restrict__ hhi, const _Float16* __restrict__ hlo,
        const float* __restrict__ gW,
        int* __restrict__ sel, float2* __restrict__ wpair) {
    int tok = blockIdx.x, t = threadIdx.x;
    __shared__ float hs[DM];
    __shared__ float red[32][8];
    __shared__ float glog[8];
    size_t base = (size_t)tok * DM;
    hs[t] = frec(hhi[base + t], hlo[base + t]);
    hs[t + 256] = frec(hhi[base + t + 256], hlo[base + t + 256]);
    __syncthreads();
    int e = t & 7, i0 = t >> 3;
    float a = 0.f;
    for (int i = i0; i < DM; i += 32) a += hs[i] * gW[i*NE + e];
    red[i0][e] = a;
    __syncthreads();
    if (t < 8) { float sv = 0.f; for (int i = 0; i < 32; ++i) sv += red[i][t]; glog[t] = sv; }
    __syncthreads();
    if (t == 0) {
        float m0 = -1e30f, m1 = -1e30f; int s0i = 0, s1i = 0;
        for (int ei = 0; ei < 8; ++ei) {
            float vv = glog[ei];
            if (vv > m0) { m1 = m0; s1i = s0i; m0 = vv; s0i = ei; }
            else if (vv > m1) { m1 = vv; s1i = ei; }
        }
        float Z = 0.f;
        for (int ei = 0; ei < 8; ++ei) Z += __expf(glog[ei] - m0);
        float2 wv;
        wv.x = 1.0f / Z;
        wv.y = __expf(m1 - m0) / Z;
        sel[tok] = s0i | (s1i << 3);
        wpair[tok] = wv;
    }
}

// ------------------------------------------------------------- head: bucket
__global__ __launch_bounds__(64) void head_bucket_kernel(
        const int* __restrict__ sel, const float2* __restrict__ wpair,
        int* __restrict__ cnt, int* __restrict__ idxlist, float* __restrict__ wlist,
        int* __restrict__ pos0, int* __restrict__ pos1) {
    int lane = threadIdx.x;
    int tok = blockIdx.x*64 + lane;
    int s = sel[tok];
    int s0 = s & 7, s1 = (s >> 3) & 7;
    float2 wv = wpair[tok];
    unsigned long long lmask = (lane == 63) ? 0x7FFFFFFFFFFFFFFFull
                                            : ((1ull << lane) - 1ull);
#pragma unroll
    for (int e = 0; e < NE; ++e) {
        unsigned long long m0 = __ballot(s0 == e);
        unsigned long long m1 = __ballot(s1 == e);
        int tot = __popcll(m0) + __popcll(m1);
        int basep = 0;
        if (lane == 0 && tot > 0) basep = atomicAdd(&cnt[e], tot);
        basep = __shfl(basep, 0);
        if (s0 == e) {
            int p = basep + __popcll(m0 & lmask);
            idxlist[e*NTOK + p] = tok; wlist[e*NTOK + p] = wv.x;
            pos0[tok] = (e << 16) | p;
        }
        if (s1 == e) {
            int p = basep + __popcll(m0) + __popcll(m1 & lmask);
            idxlist[e*NTOK + p] = tok; wlist[e*NTOK + p] = wv.y;
            pos1[tok] = (e << 16) | p;
        }
    }
}

// ------------------------------------------------------------- head: prefix
__global__ __launch_bounds__(64) void head_prefix_kernel(int* __restrict__ cnt) {
    if (threadIdx.x == 0) {
        int run = 0;
        for (int e = 0; e < NE; ++e) { cnt[8 + e] = run; run += cnt[e]; }
    }
}

// --------------------------------------------- head: grouped GEMM, fp16x2 MFMA
__global__ __launch_bounds__(256) void head_gemm_f16x2_kernel(
        const _Float16* __restrict__ hhi, const _Float16* __restrict__ hlo,
        const _Float16* __restrict__ hwhi, const _Float16* __restrict__ hwlo,
        const float* __restrict__ Hb,
        const int* __restrict__ cnt, const int* __restrict__ idxlist,
        const float* __restrict__ wlist, float* __restrict__ slotf) {
    int e = blockIdx.z;
    int cnt_e = cnt[e];
    int m0 = blockIdx.y << 6;
    if (m0 >= cnt_e) return;
    int rv = cnt_e - m0; if (rv > 64) rv = 64;
    int bn = blockIdx.x << 8;            // 0 or 256
    int pref_e = cnt[8 + e];
    int t = threadIdx.x;
    int w = t >> 6, lane = t & 63, m16 = lane & 15, quad = lane >> 4;

    __shared__ _Float16 sAh[64][40], sAl[64][40];
    __shared__ _Float16 sBh[256][40], sBl[256][40];
    __shared__ int   idxs[64];
    __shared__ float ws[64];
    if (t < 64) {
        if (t < rv) { idxs[t] = idxlist[e*NTOK + m0 + t]; ws[t] = wlist[e*NTOK + m0 + t]; }
        else        { idxs[t] = idxlist[e*NTOK + m0];     ws[t] = 0.f; }
    }
    __syncthreads();

    const _Float16* Wh = hwhi + (size_t)e*DM*DM;
    const _Float16* Wl = hwlo + (size_t)e*DM*DM;
    int ra = t >> 2, ca = (t & 3) << 3;
    f32x4 a1[4][4] = {}, a2[4][4] = {};
    for (int k0 = 0; k0 < DM; k0 += 32) {
        size_t ga = (size_t)idxs[ra]*DM + k0 + ca;
        *(uint4*)&sAh[ra][ca] = *(const uint4*)&hhi[ga];
        *(uint4*)&sAl[ra][ca] = *(const uint4*)&hlo[ga];
        size_t gb = (size_t)(bn + t)*DM + k0;
#pragma unroll
        for (int j = 0; j < 4; ++j) {
            *(uint4*)&sBh[t][j*8] = *(const uint4*)&Wh[gb + j*8];
            *(uint4*)&sBl[t][j*8] = *(const uint4*)&Wl[gb + j*8];
        }
        __syncthreads();
        f16x8 ah[4], al[4];
#pragma unroll
        for (int mt = 0; mt < 4; ++mt) {
            ah[mt] = *(const f16x8*)&sAh[mt*16 + m16][quad*8];
            al[mt] = *(const f16x8*)&sAl[mt*16 + m16][quad*8];
        }
#pragma unroll
        for (int nt = 0; nt < 4; ++nt) {
            f16x8 bh_ = *(const f16x8*)&sBh[w*64 + nt*16 + m16][quad*8];
            f16x8 bl_ = *(const f16x8*)&sBl[w*64 + nt*16 + m16][quad*8];
#pragma unroll
            for (int mt = 0; mt < 4; ++mt) {
                a1[mt][nt] = MFMA16(ah[mt], bh_, a1[mt][nt], 0, 0, 0);
                a2[mt][nt] = MFMA16(ah[mt], bl_, a2[mt][nt], 0, 0, 0);
                a2[mt][nt] = MFMA16(al[mt], bh_, a2[mt][nt], 0, 0, 0);
            }
        }
        __syncthreads();
    }
#pragma unroll
    for (int mt = 0; mt < 4; ++mt)
#pragma unroll
        for (int r = 0; r < 4; ++r) {
            int rloc = mt*16 + quad*4 + r;
            if (rloc < rv) {
                float wk = ws[rloc];
                size_t srow = (size_t)(pref_e + m0 + rloc)*DM;
#pragma unroll
                for (int nt = 0; nt < 4; ++nt) {
                    int gcol = bn + w*64 + nt*16 + m16;
                    float v = a1[mt][nt][r] + a2[mt][nt][r]*ILSC + Hb[e*DM + gcol];
                    slotf[srow + gcol] = wk * v;
                }
            }
        }
}

// ------------------------------------------------------------- head: combine+denorm
__global__ __launch_bounds__(256) void head_combine_kernel(
        const float* __restrict__ slotf,
        const int* __restrict__ pos0, const int* __restrict__ pos1,
        const int* __restrict__ cnt,
        const float* __restrict__ rw, const float* __restrict__ rb,
        const float* __restrict__ mean, const float* __restrict__ stdd,
        float* __restrict__ out) {
    int tok = blockIdx.x, t = threadIdx.x;
    int n = tok & (NVAR - 1);
    int e0enc = pos0[tok], e1enc = pos1[tok];
    size_t s0 = (size_t)(cnt[8 + (e0enc >> 16)] + (e0enc & 0xFFFF)) * DM;
    size_t s1 = (size_t)(cnt[8 + (e1enc >> 16)] + (e1enc & 0xFFFF)) * DM;
    size_t base = (size_t)tok * DM;
    float mn = mean[tok], sd = stdd[tok];
    float rwv = rw[n] + 1e-10f, rbv = rb[n];
    float o0 = slotf[s0 + t] + slotf[s1 + t];
    float o1 = slotf[s0 + t + 256] + slotf[s1 + t + 256];
    out[base + t]       = (o0 - rbv) / rwv * sd + mn;
    out[base + t + 256] = (o1 - rbv) / rwv * sd + mn;
}

// ---------------------------------------------------------------- launch
extern "C" void kernel_launch(void* const* d_in, const int* in_sizes, int n_in,
                              void* d_out, int out_size, void* d_ws, size_t ws_size,
                              hipStream_t stream) {
    const float* x       = (const float*)d_in[0];
    const float* revin_w = (const float*)d_in[1];
    const float* revin_b = (const float*)d_in[2];
    const float* emb_W   = (const float*)d_in[3];
    const float* emb_b   = (const float*)d_in[4];
    const float* Wq      = (const float*)d_in[5];
    const float* bq      = (const float*)d_in[6];
    const float* Wk      = (const float*)d_in[7];
    const float* bk      = (const float*)d_in[8];
    const float* Wv      = (const float*)d_in[9];
    const float* bv      = (const float*)d_in[10];
    const float* Wo      = (const float*)d_in[11];
    const float* bo      = (const float*)d_in[12];
    const float* ln1_w   = (const float*)d_in[13];
    const float* ln1_b   = (const float*)d_in[14];
    const float* ln2_w   = (const float*)d_in[15];
    const float* ln2_b   = (const float*)d_in[16];
    const float* gate_W  = (const float*)d_in[17];
    const float* eW1     = (const float*)d_in[18];
    const float* eb1     = (const float*)d_in[19];
    const float* eW2     = (const float*)d_in[20];
    const float* eb2     = (const float*)d_in[21];
    const float* enc_w   = (const float*)d_in[22];
    const float* enc_b   = (const float*)d_in[23];
    const float* hgW     = (const float*)d_in[24];
    const float* hW      = (const float*)d_in[25];
    const float* hb      = (const float*)d_in[26];
    float* out = (float*)d_out;

    const size_t TOKD = (size_t)NTOK * DM;   // 4194304
    float* ws   = (float*)d_ws;
    float* mean = ws;
    float* stdd = ws + 8192;
    _Float16* hhi  = (_Float16*)(ws + 16384);
    _Float16* hlo  = hhi + TOKD;
    _Float16* qhi  = hlo + TOKD;     // head stage: slotf spans qhi..klo (32 MiB)
    _Float16* qlo  = qhi + TOKD;
    _Float16* khi  = qlo + TOKD;     // also proj fp32 raw
    _Float16* klo  = khi + TOKD;
    _Float16* vthi = klo + TOKD;     // head stage: head split weights
    _Float16* vtlo = vthi + TOKD;
    _Float16* whi  = vtlo + TOKD;    // 9 transposed split weights
    _Float16* wlo  = whi + (size_t)9*DM*DM;
    int*   cnt     = (int*)(wlo + (size_t)9*DM*DM);   // [0..7]=cnt, [8..15]=prefix
    int*   idxlist = cnt + 16;
    float* wlist   = (float*)(idxlist + NE*NTOK);
    int*   sel     = (int*)(wlist + NE*NTOK);
    float2* wpair  = (float2*)(sel + NTOK);
    int*   pos0    = (int*)(wpair + NTOK);
    int*   pos1    = pos0 + NTOK;
    float* proj    = (float*)khi;
    float* slotf   = (float*)qhi;

    dim3 blk(256);
    dim3 ggemm(DM/64, NTOK/128);     // (8, 64)

    revin_stats_kernel<<<dim3(BATCH*16), blk, 0, stream>>>(x, mean, stdd);
    revin_norm_kernel<<<dim3(NVAR/32, SEQ/32, BATCH), blk, 0, stream>>>(
        x, mean, stdd, revin_w, revin_b, qhi, qlo);

    WSrcs srcs;
    srcs.p[0] = emb_W;
    for (int l = 0; l < NL; ++l) {
        srcs.p[1 + l*4 + 0] = Wq + (size_t)l*DM*DM;
        srcs.p[1 + l*4 + 1] = Wk + (size_t)l*DM*DM;
        srcs.p[1 + l*4 + 2] = Wv + (size_t)l*DM*DM;
        srcs.p[1 + l*4 + 3] = Wo + (size_t)l*DM*DM;
    }
    transpose_w_kernel<<<dim3(8, 8, 9), blk, 0, stream>>>(srcs, whi, wlo);

    gemm_f16x2_kernel<<<ggemm, blk, 0, stream>>>(
        qhi, qlo, whi, wlo, emb_b, nullptr, hhi, hlo, NTOK, SEQ, DM);

    for (int l = 0; l < NL; ++l) {
        size_t oq = (size_t)(1 + l*4 + 0)*DM*DM;
        size_t ok = (size_t)(1 + l*4 + 1)*DM*DM;
        size_t ov = (size_t)(1 + l*4 + 2)*DM*DM;
        size_t oo = (size_t)(1 + l*4 + 3)*DM*DM;
        gemm_f16x2_kernel<<<ggemm, blk, 0, stream>>>(
            hhi, hlo, whi + oq, wlo + oq, bq + l*DM, nullptr, qhi, qlo, NTOK, DM, DM);
        gemm_f16x2_kernel<<<ggemm, blk, 0, stream>>>(
            hhi, hlo, whi + ok, wlo + ok, bk + l*DM, nullptr, khi, klo, NTOK, DM, DM);
        gemm_f16x2_vt_kernel<<<ggemm, blk, 0, stream>>>(
            hhi, hlo, whi + ov, wlo + ov, bv + l*DM, vthi, vtlo);
        attn_f16x2_kernel<<<dim3(64*8), blk, 0, stream>>>(
            qhi, qlo, khi, klo, vthi, vtlo, qhi, qlo);
        gemm_f16x2_kernel<<<ggemm, blk, 0, stream>>>(
            qhi, qlo, whi + oo, wlo + oo, bo + l*DM, proj, nullptr, nullptr, NTOK, DM, DM);
        ln_kernel<<<dim3(NTOK), blk, 0, stream>>>(hhi, hlo, proj, ln1_w + l*DM, ln1_b + l*DM);
        moe_kernel<<<dim3(NTOK), blk, 0, stream>>>(
            hhi, hlo, proj, gate_W + (size_t)l*DM*NE,
            eW1 + (size_t)l*NE*DM*NF, eb1 + (size_t)l*NE*NF,
            eW2 + (size_t)l*NE*NF*DM, eb2 + (size_t)l*NE*DM);
        ln_kernel<<<dim3(NTOK), blk, 0, stream>>>(hhi, hlo, proj, ln2_w + l*DM, ln2_b + l*DM);
    }

    ln_kernel<<<dim3(NTOK), blk, 0, stream>>>(hhi, hlo, nullptr, enc_w, enc_b);

    // head expert weights -> split f16 in the (now dead) vt planes
    WSrcs hsrcs;
    for (int e = 0; e < NE; ++e) hsrcs.p[e] = hW + (size_t)e*DM*DM;
    hsrcs.p[8] = hW;   // unused
    transpose_w_kernel<<<dim3(8, 8, 8), blk, 0, stream>>>(hsrcs, vthi, vtlo);

    head_init_kernel<<<dim3(1), dim3(64), 0, stream>>>(cnt);
    head_gate_kernel<<<dim3(NTOK), blk, 0, stream>>>(hhi, hlo, hgW, sel, wpair);
    head_bucket_kernel<<<dim3(NTOK/64), dim3(64), 0, stream>>>(
        sel, wpair, cnt, idxlist, wlist, pos0, pos1);
    head_prefix_kernel<<<dim3(1), dim3(64), 0, stream>>>(cnt);
    head_gemm_f16x2_kernel<<<dim3(2, NTOK/64, NE), blk, 0, stream>>>(
        hhi, hlo, vthi, vtlo, hb, cnt, idxlist, wlist, slotf);
    head_combine_kernel<<<dim3(NTOK), blk, 0, stream>>>(
        slotf, pos0, pos1, cnt, revin_w, revin_b, mean, stdd, out);
}

// Round 9
// 1113.733 us; speedup vs baseline: 1.0489x; 1.0489x over previous
//
#include <hip/hip_runtime.h>
#include <math.h>

#define BATCH 8
#define SEQ 512
#define NVAR 1024
#define DM 512
#define NH 8
#define DH 64
#define NE 8
#define NF 8
#define NL 2
#define NTOK (BATCH*NVAR)   // 8192
#define LN_EPS 1e-5f
#define LSC 2048.0f
#define ILSC (1.0f/2048.0f)

typedef __attribute__((ext_vector_type(8))) _Float16 f16x8;
typedef __attribute__((ext_vector_type(4))) float f32x4;
#define MFMA16 __builtin_amdgcn_mfma_f32_16x16x32_f16

__device__ __forceinline__ void fsplit(float v, _Float16& hi, _Float16& lo) {
    hi = (_Float16)v;
    lo = (_Float16)((v - (float)hi) * LSC);
}
__device__ __forceinline__ float frec(_Float16 hi, _Float16 lo) {
    return (float)hi + (float)lo * ILSC;
}

// ---------------------------------------------------------------- RevIN stats
__global__ __launch_bounds__(256) void revin_stats_kernel(
        const float* __restrict__ x, float* __restrict__ mean, float* __restrict__ stdd) {
    int blk = blockIdx.x;            // b*16 + ntile
    int b = blk >> 4;
    int n0 = (blk & 15) << 6;
    int t = threadIdx.x;
    int ni = t & 63, sg = t >> 6;
    float s = 0.f, ss = 0.f;
    for (int sidx = sg; sidx < SEQ; sidx += 4) {
        float v = x[((size_t)b*SEQ + sidx)*NVAR + n0 + ni];
        s += v; ss += v*v;
    }
    __shared__ float rs[4][64], rq[4][64];
    rs[sg][ni] = s; rq[sg][ni] = ss;
    __syncthreads();
    if (t < 64) {
        float su = rs[0][t] + rs[1][t] + rs[2][t] + rs[3][t];
        float sq = rq[0][t] + rq[1][t] + rq[2][t] + rq[3][t];
        float m  = su / (float)SEQ;
        float var = sq / (float)SEQ - m*m;
        int n = n0 + t;
        mean[b*NVAR + n] = m;
        stdd[b*NVAR + n] = sqrtf(var + LN_EPS);
    }
}

// ------------------------------- RevIN normalize + transpose (split f16 out)
__global__ __launch_bounds__(256) void revin_norm_kernel(
        const float* __restrict__ x, const float* __restrict__ mean, const float* __restrict__ stdd,
        const float* __restrict__ rw, const float* __restrict__ rb,
        _Float16* __restrict__ xnhi, _Float16* __restrict__ xnlo) {
    __shared__ float tile[32][33];
    int n0 = blockIdx.x << 5, s0 = blockIdx.y << 5, b = blockIdx.z;
    int t = threadIdx.x;
    int j = t & 31, i0 = t >> 5;
    for (int ii = i0; ii < 32; ii += 8)
        tile[ii][j] = x[((size_t)b*SEQ + s0 + ii)*NVAR + n0 + j];
    __syncthreads();
    int si = t & 31, j0 = t >> 5;
    for (int nj = j0; nj < 32; nj += 8) {
        int n = n0 + nj;
        float m = mean[b*NVAR + n], sd = stdd[b*NVAR + n];
        float v = (tile[si][nj] - m) / sd * rw[n] + rb[n];
        _Float16 h_, l_; fsplit(v, h_, l_);
        size_t idx = ((size_t)b*NVAR + n)*SEQ + s0 + si;
        xnhi[idx] = h_; xnlo[idx] = l_;
    }
}

// ----------------------- weight transpose+split: [K,N] -> [N,K] f16 hi/lo
struct WSrcs { const float* p[9]; };
__global__ __launch_bounds__(256) void transpose_w_kernel(
        WSrcs srcs, _Float16* __restrict__ whi, _Float16* __restrict__ wlo) {
    const float* W = srcs.p[blockIdx.z];
    _Float16* oh = whi + (size_t)blockIdx.z * DM * DM;
    _Float16* ol = wlo + (size_t)blockIdx.z * DM * DM;
    __shared__ float tile[64][65];
    int k0 = blockIdx.x << 6, n0 = blockIdx.y << 6;
    int t = threadIdx.x;
    for (int idx = t; idx < 4096; idx += 256) {
        int k = idx >> 6, n = idx & 63;
        tile[k][n] = W[(size_t)(k0 + k)*DM + n0 + n];
    }
    __syncthreads();
    for (int idx = t; idx < 4096; idx += 256) {
        int n = idx >> 6, k = idx & 63;
        _Float16 h_, l_; fsplit(tile[k][n], h_, l_);
        size_t o = (size_t)(n0 + n)*DM + k0 + k;
        oh[o] = h_; ol[o] = l_;
    }
}

// ------------------------------------------- fp16x2 MFMA GEMM (fp32-grade)
__global__ __launch_bounds__(256) void gemm_f16x2_kernel(
        const _Float16* __restrict__ Ahg, const _Float16* __restrict__ Alg,
        const _Float16* __restrict__ Whg, const _Float16* __restrict__ Wlg,
        const float* __restrict__ bias, float* __restrict__ C,
        _Float16* __restrict__ Chi, _Float16* __restrict__ Clo,
        int M, int K, int N) {
    __shared__ _Float16 sAh[128][40], sAl[128][40];
    __shared__ _Float16 sBh[64][40],  sBl[64][40];
    int bm = blockIdx.y << 7, bn = blockIdx.x << 6;
    int t = threadIdx.x;
    int w = t >> 6, lane = t & 63, m16 = lane & 15, quad = lane >> 4;
    int ra = t >> 1,  ca = (t & 1) << 4;   // A: 128 rows x 2 groups of 16
    int rb = t >> 2,  cb = (t & 3) << 3;   // B: 64 rows x 4 groups of 8
    f32x4 a1[2][4] = {}, a2[2][4] = {};
    for (int k0 = 0; k0 < K; k0 += 32) {
        size_t ga = (size_t)(bm + ra)*K + k0 + ca;
        size_t gb = (size_t)(bn + rb)*K + k0 + cb;
        *(uint4*)&sAh[ra][ca]   = *(const uint4*)&Ahg[ga];
        *(uint4*)&sAh[ra][ca+8] = *(const uint4*)&Ahg[ga + 8];
        *(uint4*)&sAl[ra][ca]   = *(const uint4*)&Alg[ga];
        *(uint4*)&sAl[ra][ca+8] = *(const uint4*)&Alg[ga + 8];
        *(uint4*)&sBh[rb][cb]   = *(const uint4*)&Whg[gb];
        *(uint4*)&sBl[rb][cb]   = *(const uint4*)&Wlg[gb];
        __syncthreads();
        f16x8 bh_[4], bl_[4];
#pragma unroll
        for (int nt = 0; nt < 4; ++nt) {
            bh_[nt] = *(const f16x8*)&sBh[nt*16 + m16][quad*8];
            bl_[nt] = *(const f16x8*)&sBl[nt*16 + m16][quad*8];
        }
#pragma unroll
        for (int h2 = 0; h2 < 2; ++h2) {
            f16x8 ah = *(const f16x8*)&sAh[w*32 + h2*16 + m16][quad*8];
            f16x8 al = *(const f16x8*)&sAl[w*32 + h2*16 + m16][quad*8];
#pragma unroll
            for (int nt = 0; nt < 4; ++nt) {
                a1[h2][nt] = MFMA16(ah, bh_[nt], a1[h2][nt], 0, 0, 0);
                a2[h2][nt] = MFMA16(ah, bl_[nt], a2[h2][nt], 0, 0, 0);
                a2[h2][nt] = MFMA16(al, bh_[nt], a2[h2][nt], 0, 0, 0);
            }
        }
        __syncthreads();
    }
#pragma unroll
    for (int h2 = 0; h2 < 2; ++h2)
#pragma unroll
        for (int nt = 0; nt < 4; ++nt) {
            int col = bn + nt*16 + m16;
            float bv = bias[col];
#pragma unroll
            for (int r = 0; r < 4; ++r) {
                size_t row = bm + w*32 + h2*16 + quad*4 + r;
                float v = a1[h2][nt][r] + a2[h2][nt][r]*ILSC + bv;
                if (C) C[row*N + col] = v;
                if (Chi) {
                    _Float16 h_, l_; fsplit(v, h_, l_);
                    Chi[row*N + col] = h_; Clo[row*N + col] = l_;
                }
            }
        }
}

// ------------------- fp16x2 GEMM, transposed split output (V projection)
__global__ __launch_bounds__(256) void gemm_f16x2_vt_kernel(
        const _Float16* __restrict__ Ahg, const _Float16* __restrict__ Alg,
        const _Float16* __restrict__ Whg, const _Float16* __restrict__ Wlg,
        const float* __restrict__ bias,
        _Float16* __restrict__ vthi, _Float16* __restrict__ vtlo) {
    __shared__ _Float16 sAh[128][40], sAl[128][40];
    __shared__ _Float16 sBh[64][40],  sBl[64][40];
    __shared__ float Ct[128][65];
    int bm = blockIdx.y << 7, bn = blockIdx.x << 6;
    int t = threadIdx.x;
    int w = t >> 6, lane = t & 63, m16 = lane & 15, quad = lane >> 4;
    int ra = t >> 1,  ca = (t & 1) << 4;
    int rb = t >> 2,  cb = (t & 3) << 3;
    f32x4 a1[2][4] = {}, a2[2][4] = {};
    for (int k0 = 0; k0 < DM; k0 += 32) {
        size_t ga = (size_t)(bm + ra)*DM + k0 + ca;
        size_t gb = (size_t)(bn + rb)*DM + k0 + cb;
        *(uint4*)&sAh[ra][ca]   = *(const uint4*)&Ahg[ga];
        *(uint4*)&sAh[ra][ca+8] = *(const uint4*)&Ahg[ga + 8];
        *(uint4*)&sAl[ra][ca]   = *(const uint4*)&Alg[ga];
        *(uint4*)&sAl[ra][ca+8] = *(const uint4*)&Alg[ga + 8];
        *(uint4*)&sBh[rb][cb]   = *(const uint4*)&Whg[gb];
        *(uint4*)&sBl[rb][cb]   = *(const uint4*)&Wlg[gb];
        __syncthreads();
        f16x8 bh_[4], bl_[4];
#pragma unroll
        for (int nt = 0; nt < 4; ++nt) {
            bh_[nt] = *(const f16x8*)&sBh[nt*16 + m16][quad*8];
            bl_[nt] = *(const f16x8*)&sBl[nt*16 + m16][quad*8];
        }
#pragma unroll
        for (int h2 = 0; h2 < 2; ++h2) {
            f16x8 ah = *(const f16x8*)&sAh[w*32 + h2*16 + m16][quad*8];
            f16x8 al = *(const f16x8*)&sAl[w*32 + h2*16 + m16][quad*8];
#pragma unroll
            for (int nt = 0; nt < 4; ++nt) {
                a1[h2][nt] = MFMA16(ah, bh_[nt], a1[h2][nt], 0, 0, 0);
                a2[h2][nt] = MFMA16(ah, bl_[nt], a2[h2][nt], 0, 0, 0);
                a2[h2][nt] = MFMA16(al, bh_[nt], a2[h2][nt], 0, 0, 0);
            }
        }
        __syncthreads();
    }
#pragma unroll
    for (int h2 = 0; h2 < 2; ++h2)
#pragma unroll
        for (int nt = 0; nt < 4; ++nt) {
            float bv = bias[bn + nt*16 + m16];
#pragma unroll
            for (int r = 0; r < 4; ++r)
                Ct[w*32 + h2*16 + quad*4 + r][nt*16 + m16] = a1[h2][nt][r] + a2[h2][nt][r]*ILSC + bv;
        }
    __syncthreads();
    int b = bm >> 10, tokn0 = bm & 1023, hh = bn >> 6;
    int dh = t >> 2, tg = (t & 3) << 4;
    size_t rowb = ((size_t)(b*8 + hh)*64 + dh)*NVAR + tokn0;
    for (int hb = 0; hb < 2; ++hb) {
        int tl0 = hb*64 + tg;
        unsigned short hbuf[16], lbuf[16];
#pragma unroll
        for (int i = 0; i < 16; ++i) {
            _Float16 h_, l_; fsplit(Ct[tl0 + i][dh], h_, l_);
            hbuf[i] = __builtin_bit_cast(unsigned short, h_);
            lbuf[i] = __builtin_bit_cast(unsigned short, l_);
        }
        uint4 uh0, uh1, ul0, ul1;
        uh0.x = hbuf[0]|(hbuf[1]<<16);  uh0.y = hbuf[2]|(hbuf[3]<<16);
        uh0.z = hbuf[4]|(hbuf[5]<<16);  uh0.w = hbuf[6]|(hbuf[7]<<16);
        uh1.x = hbuf[8]|(hbuf[9]<<16);  uh1.y = hbuf[10]|(hbuf[11]<<16);
        uh1.z = hbuf[12]|(hbuf[13]<<16);uh1.w = hbuf[14]|(hbuf[15]<<16);
        ul0.x = lbuf[0]|(lbuf[1]<<16);  ul0.y = lbuf[2]|(lbuf[3]<<16);
        ul0.z = lbuf[4]|(lbuf[5]<<16);  ul0.w = lbuf[6]|(lbuf[7]<<16);
        ul1.x = lbuf[8]|(lbuf[9]<<16);  ul1.y = lbuf[10]|(lbuf[11]<<16);
        ul1.z = lbuf[12]|(lbuf[13]<<16);ul1.w = lbuf[14]|(lbuf[15]<<16);
        *(uint4*)&vthi[rowb + tl0]     = uh0;
        *(uint4*)&vthi[rowb + tl0 + 8] = uh1;
        *(uint4*)&vtlo[rowb + tl0]     = ul0;
        *(uint4*)&vtlo[rowb + tl0 + 8] = ul1;
    }
}

// ------------------------------------- flash attention, fp16x2 MFMA, v3
// 64 q-rows/block (grid 1024).  Q in registers.  K/V in LDS [64][64] with
// 16B-granule XOR swizzle (phys_g = g ^ (row&7)) -> no pad, ~conflict-free.
// P [64][72], wave-private rows -> no barrier between softmax and PV.
__global__ __launch_bounds__(256) void attn_f16x2_kernel(
        const _Float16* __restrict__ qh, const _Float16* __restrict__ ql,
        const _Float16* __restrict__ kh, const _Float16* __restrict__ kl,
        const _Float16* __restrict__ vth, const _Float16* __restrict__ vtl,
        _Float16* __restrict__ oh, _Float16* __restrict__ ol) {
    __shared__ _Float16 Kh[64][64], Kl[64][64];
    __shared__ _Float16 Vh[64][64], Vl[64][64];
    __shared__ _Float16 Ph[64][72], Pl[64][72];
    int blk = blockIdx.x;
    int qt = blk & 15, bh = blk >> 4;
    int b = bh >> 3, hh = bh & 7;
    int q0 = qt << 6;
    int t = threadIdx.x;
    int w = t >> 6, lane = t & 63;
    int m16 = lane & 15, quad = lane >> 4;
    size_t bbase = (size_t)b * NVAR;
    size_t vbase = (size_t)bh * DH * NVAR;

    // Q fragments in registers (loaded once)
    f16x8 qfh[2], qfl[2];
    {
        size_t rowp = (bbase + q0 + w*16 + m16)*DM + hh*DH;
#pragma unroll
        for (int ks = 0; ks < 2; ++ks) {
            qfh[ks] = *(const f16x8*)&qh[rowp + ks*32 + quad*8];
            qfl[ks] = *(const f16x8*)&ql[rowp + ks*32 + quad*8];
        }
    }
    float mrow[4] = {-1e30f,-1e30f,-1e30f,-1e30f};
    float lrow[4] = {0.f,0.f,0.f,0.f};
    f32x4 o1[4] = {}, o2[4] = {};

    for (int n0 = 0; n0 < NVAR; n0 += 64) {
        // stage K rows=key, V rows=dh; swizzled granule writes (conflict-free)
#pragma unroll
        for (int p = 0; p < 2; ++p) {
            int g = t + p*256, rr = g >> 3, cg = g & 7;
            int pc = ((cg ^ (rr & 7)) << 3);
            size_t ka = (bbase + n0 + rr)*DM + hh*DH + (cg << 3);
            *(uint4*)&Kh[rr][pc] = *(const uint4*)&kh[ka];
            *(uint4*)&Kl[rr][pc] = *(const uint4*)&kl[ka];
            size_t va = vbase + (size_t)rr*NVAR + n0 + (cg << 3);
            *(uint4*)&Vh[rr][pc] = *(const uint4*)&vth[va];
            *(uint4*)&Vl[rr][pc] = *(const uint4*)&vtl[va];
        }
        __syncthreads();

        // S = Q K^T
        f32x4 s1[4] = {}, s2[4] = {};
#pragma unroll
        for (int ks = 0; ks < 2; ++ks)
#pragma unroll
            for (int nt = 0; nt < 4; ++nt) {
                int pc = (((ks*4 + quad) ^ (m16 & 7)) << 3);
                f16x8 bh_ = *(const f16x8*)&Kh[nt*16 + m16][pc];
                f16x8 bl_ = *(const f16x8*)&Kl[nt*16 + m16][pc];
                s1[nt] = MFMA16(qfh[ks], bh_, s1[nt], 0, 0, 0);
                s2[nt] = MFMA16(qfh[ks], bl_, s2[nt], 0, 0, 0);
                s2[nt] = MFMA16(qfl[ks], bh_, s2[nt], 0, 0, 0);
            }

        // online softmax; P rows are wave-private -> no barrier needed
#pragma unroll
        for (int r = 0; r < 4; ++r) {
            float sv[4];
#pragma unroll
            for (int nt = 0; nt < 4; ++nt)
                sv[nt] = s1[nt][r]*0.125f + s2[nt][r]*(0.125f*ILSC);
            float mx = fmaxf(fmaxf(sv[0], sv[1]), fmaxf(sv[2], sv[3]));
            mx = fmaxf(mx, __shfl_xor(mx, 1));
            mx = fmaxf(mx, __shfl_xor(mx, 2));
            mx = fmaxf(mx, __shfl_xor(mx, 4));
            mx = fmaxf(mx, __shfl_xor(mx, 8));
            float mnew = fmaxf(mrow[r], mx);
            float alpha = __expf(mrow[r] - mnew);
            float rs = 0.f;
            int prow = w*16 + quad*4 + r;
#pragma unroll
            for (int nt = 0; nt < 4; ++nt) {
                float pv = __expf(sv[nt] - mnew);
                rs += pv;
                _Float16 hp, lp; fsplit(pv, hp, lp);
                Ph[prow][nt*16 + m16] = hp;
                Pl[prow][nt*16 + m16] = lp;
            }
            rs += __shfl_xor(rs, 1);
            rs += __shfl_xor(rs, 2);
            rs += __shfl_xor(rs, 4);
            rs += __shfl_xor(rs, 8);
            lrow[r] = lrow[r]*alpha + rs;
            mrow[r] = mnew;
#pragma unroll
            for (int nt = 0; nt < 4; ++nt) { o1[nt][r] *= alpha; o2[nt][r] *= alpha; }
        }

        // O += P V
#pragma unroll
        for (int ks = 0; ks < 2; ++ks) {
            f16x8 ph = *(const f16x8*)&Ph[w*16 + m16][ks*32 + quad*8];
            f16x8 pl = *(const f16x8*)&Pl[w*16 + m16][ks*32 + quad*8];
#pragma unroll
            for (int nt = 0; nt < 4; ++nt) {
                int pc = (((ks*4 + quad) ^ (m16 & 7)) << 3);
                f16x8 vh_ = *(const f16x8*)&Vh[nt*16 + m16][pc];
                f16x8 vl_ = *(const f16x8*)&Vl[nt*16 + m16][pc];
                o1[nt] = MFMA16(ph, vh_, o1[nt], 0, 0, 0);
                o2[nt] = MFMA16(ph, vl_, o2[nt], 0, 0, 0);
                o2[nt] = MFMA16(pl, vh_, o2[nt], 0, 0, 0);
            }
        }
        __syncthreads();
    }
#pragma unroll
    for (int r = 0; r < 4; ++r) {
        float inv = 1.0f / lrow[r];
        size_t rowp = (bbase + q0 + w*16 + quad*4 + r)*DM + hh*DH;
#pragma unroll
        for (int nt = 0; nt < 4; ++nt) {
            float ov = (o1[nt][r] + o2[nt][r]*ILSC) * inv;
            _Float16 h_, l_; fsplit(ov, h_, l_);
            oh[rowp + nt*16 + m16] = h_;
            ol[rowp + nt*16 + m16] = l_;
        }
    }
}

// ---------------------------------------------------------------- LayerNorm
__global__ __launch_bounds__(256) void ln_kernel(
        _Float16* __restrict__ hhi, _Float16* __restrict__ hlo,
        const float* __restrict__ res,
        const float* __restrict__ w, const float* __restrict__ b) {
    int rowi = blockIdx.x, t = threadIdx.x;
    size_t base = (size_t)rowi * DM;
    float v0 = frec(hhi[base + t], hlo[base + t]);
    float v1 = frec(hhi[base + t + 256], hlo[base + t + 256]);
    if (res) { v0 += res[base + t]; v1 += res[base + t + 256]; }
    __shared__ float rs[256], rq[256];
    rs[t] = v0 + v1; rq[t] = v0*v0 + v1*v1;
    __syncthreads();
    for (int off = 128; off > 0; off >>= 1) {
        if (t < off) { rs[t] += rs[t+off]; rq[t] += rq[t+off]; }
        __syncthreads();
    }
    float m = rs[0] / (float)DM;
    float var = rq[0] / (float)DM - m*m;
    float inv = 1.0f / sqrtf(var + LN_EPS);
    float y0 = (v0 - m)*inv * w[t]       + b[t];
    float y1 = (v1 - m)*inv * w[t + 256] + b[t + 256];
    _Float16 h0, l0, h1, l1;
    fsplit(y0, h0, l0); fsplit(y1, h1, l1);
    hhi[base + t] = h0;       hlo[base + t] = l0;
    hhi[base + t + 256] = h1; hlo[base + t + 256] = l1;
}

__device__ __forceinline__ float gelu_exact(float xv) {
    return 0.5f * xv * (1.0f + erff(xv * 0.70710678118654752f));
}

// ---------------------------------------------------------------- MoE FFN
__global__ __launch_bounds__(256) void moe_kernel(
        const _Float16* __restrict__ hhi, const _Float16* __restrict__ hlo,
        float* __restrict__ out,
        const float* __restrict__ gW, const float* __restrict__ W1, const float* __restrict__ b1,
        const float* __restrict__ W2, const float* __restrict__ b2) {
    int tok = blockIdx.x, t = threadIdx.x;
    __shared__ float hs[DM];
    __shared__ float red[32][8];
    __shared__ float glog[8];
    __shared__ float hmid[8];
    __shared__ float wsel[2];
    __shared__ int   esel[2];
    size_t base = (size_t)tok * DM;
    hs[t] = frec(hhi[base + t], hlo[base + t]);
    hs[t + 256] = frec(hhi[base + t + 256], hlo[base + t + 256]);
    __syncthreads();
    int e = t & 7, i0 = t >> 3;
    {
        float a = 0.f;
        for (int i = i0; i < DM; i += 32) a += hs[i] * gW[i*NE + e];
        red[i0][e] = a;
    }
    __syncthreads();
    if (t < 8) { float sv = 0.f; for (int i = 0; i < 32; ++i) sv += red[i][t]; glog[t] = sv; }
    __syncthreads();
    if (t == 0) {
        float m0 = -1e30f, m1 = -1e30f; int s0i = 0, s1i = 0;
        for (int ei = 0; ei < 8; ++ei) {
            float vv = glog[ei];
            if (vv > m0) { m1 = m0; s1i = s0i; m0 = vv; s0i = ei; }
            else if (vv > m1) { m1 = vv; s1i = ei; }
        }
        float Z = 0.f;
        for (int ei = 0; ei < 8; ++ei) Z += expf(glog[ei] - m0);
        wsel[0] = 1.0f / Z;
        wsel[1] = expf(m1 - m0) / Z;
        esel[0] = s0i; esel[1] = s1i;
    }
    __syncthreads();
    float o0 = 0.f, o1 = 0.f;
    for (int ks = 0; ks < 2; ++ks) {
        int ee = esel[ks]; float wk = wsel[ks];
        int f = t & 7;
        float a = 0.f;
        for (int i = i0; i < DM; i += 32) a += hs[i] * W1[((size_t)ee*DM + i)*NF + f];
        red[i0][f] = a;
        __syncthreads();
        if (t < 8) {
            float sv = b1[ee*NF + t];
            for (int i = 0; i < 32; ++i) sv += red[i][t];
            hmid[t] = gelu_exact(sv);
        }
        __syncthreads();
        float s0v = b2[ee*DM + t], s1v = b2[ee*DM + t + 256];
#pragma unroll
        for (int i = 0; i < NF; ++i) {
            float hm = hmid[i];
            const float* wp = W2 + ((size_t)ee*NF + i)*DM;
            s0v += hm * wp[t]; s1v += hm * wp[t + 256];
        }
        o0 += wk * s0v; o1 += wk * s1v;
        __syncthreads();
    }
    out[base + t] = o0; out[base + t + 256] = o1;
}

// ------------------------------------------------------------- head: init
__global__ __launch_bounds__(64) void head_init_kernel(int* __restrict__ cnt) {
    if (threadIdx.x < NE) cnt[threadIdx.x] = 0;
}

// ------------------------------------------------------------- head: gate
__global__ __launch_bounds__(256) void head_gate_kernel(
        const _Float16* __restrict__ hhi, const _Float16* __restrict__ hlo,
        const float* __restrict__ gW,
        int* __restrict__ sel, float2* __restrict__ wpair) {
    int tok = blockIdx.x, t = threadIdx.x;
    __shared__ float hs[DM];
    __shared__ float red[32][8];
    __shared__ float glog[8];
    size_t base = (size_t)tok * DM;
    hs[t] = frec(hhi[base + t], hlo[base + t]);
    hs[t + 256] = frec(hhi[base + t + 256], hlo[base + t + 256]);
    __syncthreads();
    int e = t & 7, i0 = t >> 3;
    float a = 0.f;
    for (int i = i0; i < DM; i += 32) a += hs[i] * gW[i*NE + e];
    red[i0][e] = a;
    __syncthreads();
    if (t < 8) { float sv = 0.f; for (int i = 0; i < 32; ++i) sv += red[i][t]; glog[t] = sv; }
    __syncthreads();
    if (t == 0) {
        float m0 = -1e30f, m1 = -1e30f; int s0i = 0, s1i = 0;
        for (int ei = 0; ei < 8; ++ei) {
            float vv = glog[ei];
            if (vv > m0) { m1 = m0; s1i = s0i; m0 = vv; s0i = ei; }
            else if (vv > m1) { m1 = vv; s1i = ei; }
        }
        float Z = 0.f;
        for (int ei = 0; ei < 8; ++ei) Z += __expf(glog[ei] - m0);
        float2 wv;
        wv.x = 1.0f / Z;
        wv.y = __expf(m1 - m0) / Z;
        sel[tok] = s0i | (s1i << 3);
        wpair[tok] = wv;
    }
}

// ------------------------------------------------------------- head: bucket
__global__ __launch_bounds__(64) void head_bucket_kernel(
        const int* __restrict__ sel, const float2* __restrict__ wpair,
        int* __restrict__ cnt, int* __restrict__ idxlist, float* __restrict__ wlist,
        int* __restrict__ pos0, int* __restrict__ pos1) {
    int lane = threadIdx.x;
    int tok = blockIdx.x*64 + lane;
    int s = sel[tok];
    int s0 = s & 7, s1 = (s >> 3) & 7;
    float2 wv = wpair[tok];
    unsigned long long lmask = (lane == 63) ? 0x7FFFFFFFFFFFFFFFull
                                            : ((1ull << lane) - 1ull);
#pragma unroll
    for (int e = 0; e < NE; ++e) {
        unsigned long long m0 = __ballot(s0 == e);
        unsigned long long m1 = __ballot(s1 == e);
        int tot = __popcll(m0) + __popcll(m1);
        int basep = 0;
        if (lane == 0 && tot > 0) basep = atomicAdd(&cnt[e], tot);
        basep = __shfl(basep, 0);
        if (s0 == e) {
            int p = basep + __popcll(m0 & lmask);
            idxlist[e*NTOK + p] = tok; wlist[e*NTOK + p] = wv.x;
            pos0[tok] = (e << 16) | p;
        }
        if (s1 == e) {
            int p = basep + __popcll(m0) + __popcll(m1 & lmask);
            idxlist[e*NTOK + p] = tok; wlist[e*NTOK + p] = wv.y;
            pos1[tok] = (e << 16) | p;
        }
    }
}

// ------------------------------------------------------------- head: prefix
__global__ __launch_bounds__(64) void head_prefix_kernel(int* __restrict__ cnt) {
    if (threadIdx.x == 0) {
        int run = 0;
        for (int e = 0; e < NE; ++e) { cnt[8 + e] = run; run += cnt[e]; }
    }
}

// --------------------------------------------- head: grouped GEMM, fp16x2 MFMA
__global__ __launch_bounds__(256) void head_gemm_f16x2_kernel(
        const _Float16* __restrict__ hhi, const _Float16* __restrict__ hlo,
        const _Float16* __restrict__ hwhi, const _Float16* __restrict__ hwlo,
        const float* __restrict__ Hb,
        const int* __restrict__ cnt, const int* __restrict__ idxlist,
        const float* __restrict__ wlist, float* __restrict__ slotf) {
    int e = blockIdx.z;
    int cnt_e = cnt[e];
    int m0 = blockIdx.y << 6;
    if (m0 >= cnt_e) return;
    int rv = cnt_e - m0; if (rv > 64) rv = 64;
    int bn = blockIdx.x << 8;            // 0 or 256
    int pref_e = cnt[8 + e];
    int t = threadIdx.x;
    int w = t >> 6, lane = t & 63, m16 = lane & 15, quad = lane >> 4;

    __shared__ _Float16 sAh[64][40], sAl[64][40];
    __shared__ _Float16 sBh[256][40], sBl[256][40];
    __shared__ int   idxs[64];
    __shared__ float ws[64];
    if (t < 64) {
        if (t < rv) { idxs[t] = idxlist[e*NTOK + m0 + t]; ws[t] = wlist[e*NTOK + m0 + t]; }
        else        { idxs[t] = idxlist[e*NTOK + m0];     ws[t] = 0.f; }
    }
    __syncthreads();

    const _Float16* Wh = hwhi + (size_t)e*DM*DM;
    const _Float16* Wl = hwlo + (size_t)e*DM*DM;
    int ra = t >> 2, ca = (t & 3) << 3;
    f32x4 a1[4][4] = {}, a2[4][4] = {};
    for (int k0 = 0; k0 < DM; k0 += 32) {
        size_t ga = (size_t)idxs[ra]*DM + k0 + ca;
        *(uint4*)&sAh[ra][ca] = *(const uint4*)&hhi[ga];
        *(uint4*)&sAl[ra][ca] = *(const uint4*)&hlo[ga];
        size_t gb = (size_t)(bn + t)*DM + k0;
#pragma unroll
        for (int j = 0; j < 4; ++j) {
            *(uint4*)&sBh[t][j*8] = *(const uint4*)&Wh[gb + j*8];
            *(uint4*)&sBl[t][j*8] = *(const uint4*)&Wl[gb + j*8];
        }
        __syncthreads();
        f16x8 ah[4], al[4];
#pragma unroll
        for (int mt = 0; mt < 4; ++mt) {
            ah[mt] = *(const f16x8*)&sAh[mt*16 + m16][quad*8];
            al[mt] = *(const f16x8*)&sAl[mt*16 + m16][quad*8];
        }
#pragma unroll
        for (int nt = 0; nt < 4; ++nt) {
            f16x8 bh_ = *(const f16x8*)&sBh[w*64 + nt*16 + m16][quad*8];
            f16x8 bl_ = *(const f16x8*)&sBl[w*64 + nt*16 + m16][quad*8];
#pragma unroll
            for (int mt = 0; mt < 4; ++mt) {
                a1[mt][nt] = MFMA16(ah[mt], bh_, a1[mt][nt], 0, 0, 0);
                a2[mt][nt] = MFMA16(ah[mt], bl_, a2[mt][nt], 0, 0, 0);
                a2[mt][nt] = MFMA16(al[mt], bh_, a2[mt][nt], 0, 0, 0);
            }
        }
        __syncthreads();
    }
#pragma unroll
    for (int mt = 0; mt < 4; ++mt)
#pragma unroll
        for (int r = 0; r < 4; ++r) {
            int rloc = mt*16 + quad*4 + r;
            if (rloc < rv) {
                float wk = ws[rloc];
                size_t srow = (size_t)(pref_e + m0 + rloc)*DM;
#pragma unroll
                for (int nt = 0; nt < 4; ++nt) {
                    int gcol = bn + w*64 + nt*16 + m16;
                    float v = a1[mt][nt][r] + a2[mt][nt][r]*ILSC + Hb[e*DM + gcol];
                    slotf[srow + gcol] = wk * v;
                }
            }
        }
}

// ------------------------------------------------------------- head: combine+denorm
__global__ __launch_bounds__(256) void head_combine_kernel(
        const float* __restrict__ slotf,
        const int* __restrict__ pos0, const int* __restrict__ pos1,
        const int* __restrict__ cnt,
        const float* __restrict__ rw, const float* __restrict__ rb,
        const float* __restrict__ mean, const float* __restrict__ stdd,
        float* __restrict__ out) {
    int tok = blockIdx.x, t = threadIdx.x;
    int n = tok & (NVAR - 1);
    int e0enc = pos0[tok], e1enc = pos1[tok];
    size_t s0 = (size_t)(cnt[8 + (e0enc >> 16)] + (e0enc & 0xFFFF)) * DM;
    size_t s1 = (size_t)(cnt[8 + (e1enc >> 16)] + (e1enc & 0xFFFF)) * DM;
    size_t base = (size_t)tok * DM;
    float mn = mean[tok], sd = stdd[tok];
    float rwv = rw[n] + 1e-10f, rbv = rb[n];
    float o0 = slotf[s0 + t] + slotf[s1 + t];
    float o1 = slotf[s0 + t + 256] + slotf[s1 + t + 256];
    out[base + t]       = (o0 - rbv) / rwv * sd + mn;
    out[base + t + 256] = (o1 - rbv) / rwv * sd + mn;
}

// ---------------------------------------------------------------- launch
extern "C" void kernel_launch(void* const* d_in, const int* in_sizes, int n_in,
                              void* d_out, int out_size, void* d_ws, size_t ws_size,
                              hipStream_t stream) {
    const float* x       = (const float*)d_in[0];
    const float* revin_w = (const float*)d_in[1];
    const float* revin_b = (const float*)d_in[2];
    const float* emb_W   = (const float*)d_in[3];
    const float* emb_b   = (const float*)d_in[4];
    const float* Wq      = (const float*)d_in[5];
    const float* bq      = (const float*)d_in[6];
    const float* Wk      = (const float*)d_in[7];
    const float* bk      = (const float*)d_in[8];
    const float* Wv      = (const float*)d_in[9];
    const float* bv      = (const float*)d_in[10];
    const float* Wo      = (const float*)d_in[11];
    const float* bo      = (const float*)d_in[12];
    const float* ln1_w   = (const float*)d_in[13];
    const float* ln1_b   = (const float*)d_in[14];
    const float* ln2_w   = (const float*)d_in[15];
    const float* ln2_b   = (const float*)d_in[16];
    const float* gate_W  = (const float*)d_in[17];
    const float* eW1     = (const float*)d_in[18];
    const float* eb1     = (const float*)d_in[19];
    const float* eW2     = (const float*)d_in[20];
    const float* eb2     = (const float*)d_in[21];
    const float* enc_w   = (const float*)d_in[22];
    const float* enc_b   = (const float*)d_in[23];
    const float* hgW     = (const float*)d_in[24];
    const float* hW      = (const float*)d_in[25];
    const float* hb      = (const float*)d_in[26];
    float* out = (float*)d_out;

    const size_t TOKD = (size_t)NTOK * DM;   // 4194304
    float* ws   = (float*)d_ws;
    float* mean = ws;
    float* stdd = ws + 8192;
    _Float16* hhi  = (_Float16*)(ws + 16384);
    _Float16* hlo  = hhi + TOKD;
    _Float16* qhi  = hlo + TOKD;     // head stage: slotf spans qhi..klo (32 MiB)
    _Float16* qlo  = qhi + TOKD;
    _Float16* khi  = qlo + TOKD;     // also proj fp32 raw
    _Float16* klo  = khi + TOKD;
    _Float16* vthi = klo + TOKD;     // head stage: head split weights
    _Float16* vtlo = vthi + TOKD;
    _Float16* whi  = vtlo + TOKD;    // 9 transposed split weights
    _Float16* wlo  = whi + (size_t)9*DM*DM;
    int*   cnt     = (int*)(wlo + (size_t)9*DM*DM);   // [0..7]=cnt, [8..15]=prefix
    int*   idxlist = cnt + 16;
    float* wlist   = (float*)(idxlist + NE*NTOK);
    int*   sel     = (int*)(wlist + NE*NTOK);
    float2* wpair  = (float2*)(sel + NTOK);
    int*   pos0    = (int*)(wpair + NTOK);
    int*   pos1    = pos0 + NTOK;
    float* proj    = (float*)khi;
    float* slotf   = (float*)qhi;

    dim3 blk(256);
    dim3 ggemm(DM/64, NTOK/128);     // (8, 64)

    revin_stats_kernel<<<dim3(BATCH*16), blk, 0, stream>>>(x, mean, stdd);
    revin_norm_kernel<<<dim3(NVAR/32, SEQ/32, BATCH), blk, 0, stream>>>(
        x, mean, stdd, revin_w, revin_b, qhi, qlo);

    WSrcs srcs;
    srcs.p[0] = emb_W;
    for (int l = 0; l < NL; ++l) {
        srcs.p[1 + l*4 + 0] = Wq + (size_t)l*DM*DM;
        srcs.p[1 + l*4 + 1] = Wk + (size_t)l*DM*DM;
        srcs.p[1 + l*4 + 2] = Wv + (size_t)l*DM*DM;
        srcs.p[1 + l*4 + 3] = Wo + (size_t)l*DM*DM;
    }
    transpose_w_kernel<<<dim3(8, 8, 9), blk, 0, stream>>>(srcs, whi, wlo);

    gemm_f16x2_kernel<<<ggemm, blk, 0, stream>>>(
        qhi, qlo, whi, wlo, emb_b, nullptr, hhi, hlo, NTOK, SEQ, DM);

    for (int l = 0; l < NL; ++l) {
        size_t oq = (size_t)(1 + l*4 + 0)*DM*DM;
        size_t ok = (size_t)(1 + l*4 + 1)*DM*DM;
        size_t ov = (size_t)(1 + l*4 + 2)*DM*DM;
        size_t oo = (size_t)(1 + l*4 + 3)*DM*DM;
        gemm_f16x2_kernel<<<ggemm, blk, 0, stream>>>(
            hhi, hlo, whi + oq, wlo + oq, bq + l*DM, nullptr, qhi, qlo, NTOK, DM, DM);
        gemm_f16x2_kernel<<<ggemm, blk, 0, stream>>>(
            hhi, hlo, whi + ok, wlo + ok, bk + l*DM, nullptr, khi, klo, NTOK, DM, DM);
        gemm_f16x2_vt_kernel<<<ggemm, blk, 0, stream>>>(
            hhi, hlo, whi + ov, wlo + ov, bv + l*DM, vthi, vtlo);
        attn_f16x2_kernel<<<dim3(64*16), blk, 0, stream>>>(
            qhi, qlo, khi, klo, vthi, vtlo, qhi, qlo);
        gemm_f16x2_kernel<<<ggemm, blk, 0, stream>>>(
            qhi, qlo, whi + oo, wlo + oo, bo + l*DM, proj, nullptr, nullptr, NTOK, DM, DM);
        ln_kernel<<<dim3(NTOK), blk, 0, stream>>>(hhi, hlo, proj, ln1_w + l*DM, ln1_b + l*DM);
        moe_kernel<<<dim3(NTOK), blk, 0, stream>>>(
            hhi, hlo, proj, gate_W + (size_t)l*DM*NE,
            eW1 + (size_t)l*NE*DM*NF, eb1 + (size_t)l*NE*NF,
            eW2 + (size_t)l*NE*NF*DM, eb2 + (size_t)l*NE*DM);
        ln_kernel<<<dim3(NTOK), blk, 0, stream>>>(hhi, hlo, proj, ln2_w + l*DM, ln2_b + l*DM);
    }

    ln_kernel<<<dim3(NTOK), blk, 0, stream>>>(hhi, hlo, nullptr, enc_w, enc_b);

    // head expert weights -> split f16 in the (now dead) vt planes
    WSrcs hsrcs;
    for (int e = 0; e < NE; ++e) hsrcs.p[e] = hW + (size_t)e*DM*DM;
    hsrcs.p[8] = hW;   // unused
    transpose_w_kernel<<<dim3(8, 8, 8), blk, 0, stream>>>(hsrcs, vthi, vtlo);

    head_init_kernel<<<dim3(1), dim3(64), 0, stream>>>(cnt);
    head_gate_kernel<<<dim3(NTOK), blk, 0, stream>>>(hhi, hlo, hgW, sel, wpair);
    head_bucket_kernel<<<dim3(NTOK/64), dim3(64), 0, stream>>>(
        sel, wpair, cnt, idxlist, wlist, pos0, pos1);
    head_prefix_kernel<<<dim3(1), dim3(64), 0, stream>>>(cnt);
    head_gemm_f16x2_kernel<<<dim3(2, NTOK/64, NE), blk, 0, stream>>>(
        hhi, hlo, vthi, vtlo, hb, cnt, idxlist, wlist, slotf);
    head_combine_kernel<<<dim3(NTOK), blk, 0, stream>>>(
        slotf, pos0, pos1, cnt, revin_w, revin_b, mean, stdd, out);
}